// Round 13
// baseline (963.438 us; speedup 1.0000x reference)
//
#include <hip/hip_runtime.h>
#include <math.h>

#define NB 8
#define N0 8192
#define N1 1024
#define N2 512
#define N3C 256
#define CFEAT 256
#define KNN 16
#define PSTRIDE 256   // max partial slots per (b,d) row (NS <= 256)

typedef float v2f __attribute__((ext_vector_type(2)));

static __device__ __forceinline__ v2f pk_add(v2f a, v2f b) {
  v2f r; asm("v_pk_add_f32 %0, %1, %2" : "=v"(r) : "v"(a), "v"(b)); return r;
}
static __device__ __forceinline__ v2f pk_mul(v2f a, v2f b) {
  v2f r; asm("v_pk_mul_f32 %0, %1, %2" : "=v"(r) : "v"(a), "v"(b)); return r;
}

// ---- f64-key DPP wave64 max (bound_ctrl=false safe: max idempotent) ----
template <int CTRL, int RM>
static __device__ __forceinline__ double dpp_fmax64(double m) {
  int mh = __double2hiint(m), ml = __double2loint(m);
  int ch = __builtin_amdgcn_update_dpp(mh, mh, CTRL, RM, 0xF, false);
  int cl = __builtin_amdgcn_update_dpp(ml, ml, CTRL, RM, 0xF, false);
  return fmax(m, __hiloint2double(ch, cl));
}
static __device__ __forceinline__ double wave_fmax64(double m) {
  m = dpp_fmax64<0x111, 0xF>(m);
  m = dpp_fmax64<0x112, 0xF>(m);
  m = dpp_fmax64<0x114, 0xF>(m);
  m = dpp_fmax64<0x118, 0xF>(m);
  m = dpp_fmax64<0x142, 0xA>(m);
  m = dpp_fmax64<0x143, 0xC>(m);   // lane 63 complete
  return m;
}

// ---- (key,idx) u64 DPP min for kNN (proven) ----
template <int CTRL, int RM>
static __device__ __forceinline__ void dpp_minstep(uint32_t& hi, uint32_t& lo) {
  uint32_t chi = (uint32_t)__builtin_amdgcn_update_dpp((int)hi, (int)hi, CTRL, RM, 0xF, false);
  uint32_t clo = (uint32_t)__builtin_amdgcn_update_dpp((int)lo, (int)lo, CTRL, RM, 0xF, false);
  unsigned long long cand = ((unsigned long long)chi << 32) | clo;
  unsigned long long cur  = ((unsigned long long)hi  << 32) | lo;
  if (cand < cur) { hi = chi; lo = clo; }
}
static __device__ __forceinline__ void wave_min_pair(uint32_t& hi, uint32_t& lo) {
  dpp_minstep<0x111, 0xF>(hi, lo);
  dpp_minstep<0x112, 0xF>(hi, lo);
  dpp_minstep<0x114, 0xF>(hi, lo);
  dpp_minstep<0x118, 0xF>(hi, lo);
  dpp_minstep<0x142, 0xA>(hi, lo);
  dpp_minstep<0x143, 0xC>(hi, lo);
}

// ---- DPP wave64 f32 SUM: bound_ctrl=TRUE (invalid lanes contribute 0) ----
template <int CTRL, int RM>
static __device__ __forceinline__ float dpp_addstep(float x) {
  int xi = __float_as_int(x);
  int sv = __builtin_amdgcn_update_dpp(xi, xi, CTRL, RM, 0xF, true);
  return x + __int_as_float(sv);
}
static __device__ __forceinline__ float wave_sum63(float x) {
  x = dpp_addstep<0x111, 0xF>(x);
  x = dpp_addstep<0x112, 0xF>(x);
  x = dpp_addstep<0x114, 0xF>(x);
  x = dpp_addstep<0x118, 0xF>(x);
  x = dpp_addstep<0x142, 0xA>(x);
  x = dpp_addstep<0x143, 0xC>(x);
  return x;   // lane 63 = wave sum
}

// ---------------- 4-wave cooperative FPS scan, v3 ----------------
// Wave w owns contiguous [w*N/4, (w+1)*N/4); lane owns PPW consecutive points.
// Keys {hi=dist_bits, lo=~idx} unique -> max order-free; ~idx = lowest-idx ties.
// v3: winner coords come from the OWNER LANE'S REGISTERS (uniform select +
// readlane — no gather, no bank conflicts), published with the key; the
// dependent post-barrier sm[far] read is gone.
template <int N>
static __device__ void fps_scan4(const float4* sm, double* kbuf, float4* cbuf, int* idx_out) {
  constexpr int PPW = N / 256;        // 2 (N2) or 4 (N1)
  constexpr int L2P = (PPW == 2) ? 1 : 2;
  int tid = threadIdx.x;
  int lane = tid & 63;
  int w = tid >> 6;
  int base = w * (N / 4) + lane * PPW;
  v2f px[PPW / 2], py[PPW / 2], pz[PPW / 2];
  float dist[PPW];
  int nlo[PPW];
#pragma unroll
  for (int k = 0; k < PPW / 2; k++) {
    float4 a = sm[base + 2 * k];
    float4 c = sm[base + 2 * k + 1];
    px[k] = v2f{a.x, c.x}; py[k] = v2f{a.y, c.y}; pz[k] = v2f{a.z, c.z};
    dist[2 * k] = 1e10f; dist[2 * k + 1] = 1e10f;
    nlo[2 * k] = ~(base + 2 * k); nlo[2 * k + 1] = ~(base + 2 * k + 1);
  }
  int far = 0;
  float4 f0 = sm[0];
  float fx = f0.x, fy = f0.y, fz = f0.z;
  for (int t = 0; t < N; t++) {
    if (tid == 0) idx_out[t] = far;           // scan emits carry BEFORE update
    v2f vfx = v2f{-fx, -fx}, vfy = v2f{-fy, -fy}, vfz = v2f{-fz, -fz};
#pragma unroll
    for (int k = 0; k < PPW / 2; k++) {       // x+(-y)==x-y exactly; pk rn per comp
      v2f dx = pk_add(px[k], vfx);
      v2f dy = pk_add(py[k], vfy);
      v2f dz = pk_add(pz[k], vfz);
      v2f dd = pk_add(pk_add(pk_mul(dx, dx), pk_mul(dy, dy)), pk_mul(dz, dz));
      dist[2 * k]     = fminf(dist[2 * k],     dd.x);
      dist[2 * k + 1] = fminf(dist[2 * k + 1], dd.y);
    }
    double tv[PPW / 2];
#pragma unroll
    for (int i = 0; i < PPW / 2; i++)
      tv[i] = fmax(__hiloint2double(__float_as_int(dist[2 * i]),     nlo[2 * i]),
                   __hiloint2double(__float_as_int(dist[2 * i + 1]), nlo[2 * i + 1]));
#pragma unroll
    for (int s = PPW / 4; s >= 1; s >>= 1)
#pragma unroll
      for (int i = 0; i < s; i++) tv[i] = fmax(tv[i], tv[i + s]);
    double m = wave_fmax64(tv[0]);            // valid in lane 63
    // broadcast wave key to all lanes (2 readlanes)
    double M = __hiloint2double(__builtin_amdgcn_readlane(__double2hiint(m), 63),
                                __builtin_amdgcn_readlane(__double2loint(m), 63));
    int widx = ~__double2loint(M);            // wave winner global idx (uniform)
    int loc = widx - w * (N / 4);
    int wl = loc >> L2P;                      // owner lane (uniform)
    int j = loc & (PPW - 1);                  // slot within lane (uniform)
    float sx, sy, sz;
    if constexpr (PPW == 2) {
      sx = (j & 1) ? px[0].y : px[0].x;
      sy = (j & 1) ? py[0].y : py[0].x;
      sz = (j & 1) ? pz[0].y : pz[0].x;
    } else {
      v2f qx = (j >> 1) ? px[1] : px[0];
      v2f qy = (j >> 1) ? py[1] : py[0];
      v2f qz = (j >> 1) ? pz[1] : pz[0];
      sx = (j & 1) ? qx.y : qx.x;
      sy = (j & 1) ? qy.y : qy.x;
      sz = (j & 1) ? qz.y : qz.x;
    }
    float cx = __int_as_float(__builtin_amdgcn_readlane(__float_as_int(sx), wl));
    float cy = __int_as_float(__builtin_amdgcn_readlane(__float_as_int(sy), wl));
    float cz = __int_as_float(__builtin_amdgcn_readlane(__float_as_int(sz), wl));
    int p = t & 1;                            // double-buffered slots
    if (lane == 63) {
      kbuf[p * 4 + w] = M;
      cbuf[p * 4 + w] = make_float4(cx, cy, cz, 0.f);
    }
    __syncthreads();
    // parallel 4-struct broadcast read + in-register select (keys unique)
    const double* kq = kbuf + p * 4;
    const float4* cq = cbuf + p * 4;
    double k0 = kq[0], k1 = kq[1], k2 = kq[2], k3 = kq[3];
    float4 c0 = cq[0], c1 = cq[1], c2 = cq[2], c3 = cq[3];
    double m01 = fmax(k0, k1); float4 s01 = (k1 > k0) ? c1 : c0;
    double m23 = fmax(k2, k3); float4 s23 = (k3 > k2) ? c3 : c2;
    double MG  = fmax(m01, m23); float4 cw = (m23 > m01) ? s23 : s01;
    far = ~__double2loint(MG);
    fx = cw.x; fy = cw.y; fz = cw.z;
  }
}

// ---------------- corr unit (proven) ----------------
static __device__ void corr_unit(int u, const float* __restrict__ f1, const float* __restrict__ f2,
                                 const float* __restrict__ p1, const float* __restrict__ p2,
                                 const float* __restrict__ eps_in, float* __restrict__ flow0,
                                 char* smem) {
  float* f1c = (float*)smem;
  float* red = f1c + 256;
  float* p1s = red + 16;
  int b = u / N3C, n = u % N3C;
  int m = threadIdx.x;
  f1c[m] = f1[((size_t)b * CFEAT + m) * N3C + n];
  if (m < 3) p1s[m] = p1[((size_t)b * 3 + m) * N3C + n];
  __syncthreads();
  float eps = expf(eps_in[0]) + 0.03f;
  const float* f2b = f2 + (size_t)b * CFEAT * N3C;
  float dot = 0.f, s1 = 0.f, s2 = 0.f;
  for (int c = 0; c < CFEAT; c++) {
    float a = f1c[c];
    float v = f2b[(size_t)c * N3C + m];
    dot += a * v; s1 += a * a; s2 += v * v;
  }
  float rn1 = 1.0f / sqrtf(s1 + 1e-8f);
  float rn2 = 1.0f / sqrtf(s2 + 1e-8f);
  float Cv = 1.0f - dot * rn1 * rn2;
  float p2x = p2[((size_t)b * 3 + 0) * N3C + m];
  float p2y = p2[((size_t)b * 3 + 1) * N3C + m];
  float p2z = p2[((size_t)b * 3 + 2) * N3C + m];
  float n1v = p1s[0] * p1s[0] + p1s[1] * p1s[1] + p1s[2] * p1s[2];
  float n2v = p2x * p2x + p2y * p2y + p2z * p2z;
  float dd = n1v + n2v - 2.0f * (p1s[0] * p2x + p1s[1] * p2y + p1s[2] * p2z);
  float corr = (dd < 100.0f) ? expf(-Cv / eps) : 0.0f;
  float s0 = corr, t1 = corr * p2x, t2 = corr * p2y, t3 = corr * p2z;
  for (int off = 32; off; off >>= 1) {
    s0 += __shfl_xor(s0, off, 64); t1 += __shfl_xor(t1, off, 64);
    t2 += __shfl_xor(t2, off, 64); t3 += __shfl_xor(t3, off, 64);
  }
  int wid = threadIdx.x >> 6;
  if ((threadIdx.x & 63) == 0) { red[wid] = s0; red[4 + wid] = t1; red[8 + wid] = t2; red[12 + wid] = t3; }
  __syncthreads();
  if (threadIdx.x == 0) {
    float r0 = red[0] + red[1] + red[2] + red[3];
    float r1 = red[4] + red[5] + red[6] + red[7];
    float r2 = red[8] + red[9] + red[10] + red[11];
    float r3 = red[12] + red[13] + red[14] + red[15];
    float inv = 1.0f / (r0 + 1e-8f);
    float* fo = flow0 + ((size_t)b * N3C + n) * 3;
    fo[0] = r1 * inv - p1s[0];
    fo[1] = r2 * inv - p1s[1];
    fo[2] = r3 * inv - p1s[2];
  }
  __syncthreads();
}

// ---------------- launch 1: FPS (blocks 0..15, 4-wave v3) || corr (blocks 16+) ----------------
__global__ void fps_corr_kernel(const float* __restrict__ xyz_l2, const float* __restrict__ xyz_l1,
                                int* __restrict__ fps1, int* __restrict__ fps2,
                                const float* __restrict__ f1, const float* __restrict__ f2,
                                const float* __restrict__ p1, const float* __restrict__ p2,
                                const float* __restrict__ eps_in, float* __restrict__ flow0) {
  __shared__ __align__(16) char smem[16384 + 64 + 128];
  int blk = blockIdx.x, tid = threadIdx.x;
  if (blk < 2 * NB) {
    float4* sm = (float4*)smem;
    double* kbuf = (double*)(smem + 16384);
    float4* cbuf = (float4*)(smem + 16384 + 64);
    if (blk < NB) {
      const float* xb = xyz_l2 + (size_t)blk * 3 * N2;
      for (int i = tid; i < N2; i += 256) {
        float4 v; v.x = xb[i]; v.y = xb[N2 + i]; v.z = xb[2 * N2 + i]; v.w = 0.f;
        sm[i] = v;
      }
      __syncthreads();
      fps_scan4<N2>(sm, kbuf, cbuf, fps1 + (size_t)blk * N2);
    } else {
      int b = blk - NB;
      const float* xb = xyz_l1 + (size_t)b * 3 * N1;
      for (int i = tid; i < N1; i += 256) {
        float4 v; v.x = xb[i]; v.y = xb[N1 + i]; v.z = xb[2 * N1 + i]; v.w = 0.f;
        sm[i] = v;
      }
      __syncthreads();
      fps_scan4<N1>(sm, kbuf, cbuf, fps2 + (size_t)b * N1);
    }
  } else {
    for (int u = blk - 2 * NB; u < NB * N3C; u += (int)gridDim.x - 2 * NB)
      corr_unit(u, f1, f2, p1, p2, eps_in, flow0, smem);
  }
}

// ---------------- kNN (proven) ----------------
template <int S, int PPL>
static __device__ void knn_impl(const float* __restrict__ xyz, const int* __restrict__ fps_idx,
                                int* __restrict__ knn_out, int gw) {
  int lane = threadIdx.x & 63;
  int b = gw / S, s = gw % S;
  int center = fps_idx[(size_t)b * S + s];
  const float* xb = xyz + (size_t)b * 3 * S;
  float cx = xb[center], cy = xb[S + center], cz = xb[2 * S + center];
  float cn = cx * cx + cy * cy + cz * cz;
  uint32_t kb[PPL];
#pragma unroll
  for (int j = 0; j < PPL; j++) {
    int g = lane * PPL + j;
    float x = xb[g], y = xb[S + g], z = xb[2 * S + g];
    float pn = x * x + y * y + z * z;
    float d = cn + pn - 2.0f * (cx * x + cy * y + cz * z);
    uint32_t bts = __float_as_uint(d);
    kb[j] = bts ^ ((uint32_t)((int)bts >> 31) | 0x80000000u);
  }
  int* ob = knn_out + ((size_t)b * S + s) * KNN;
  for (int r = 0; r < KNN; r++) {
    uint32_t bh = 0xFFFFFFFFu, bl = 0xFFFFFFFFu;
#pragma unroll
    for (int j = 0; j < PPL; j++) {
      unsigned long long cand = ((unsigned long long)kb[j] << 32) | (uint32_t)(lane * PPL + j);
      unsigned long long cur  = ((unsigned long long)bh << 32) | bl;
      if (cand < cur) { bh = kb[j]; bl = (uint32_t)(lane * PPL + j); }
    }
    wave_min_pair(bh, bl);
    uint32_t widx = (uint32_t)__builtin_amdgcn_readlane((int)bl, 63);
    if (lane == 0) ob[r] = (int)widx;
#pragma unroll
    for (int j = 0; j < PPL; j++)
      if ((uint32_t)(lane * PPL + j) == widx) kb[j] = 0xFFFFFFFFu;
  }
}

// ---------------- 3-NN interpolation unit (proven) ----------------
template <int C, bool TOUT, int S>
static __device__ void fprop_unit(int u, int Npts, const float* __restrict__ xyz1,
                                  const float* __restrict__ xyz2, const float* __restrict__ featT,
                                  float* __restrict__ out, float* smem) {
  float* x2s = smem;
  float* n2s = x2s + 3 * S;
  int tilesPerB = Npts / 256;
  int b = u / tilesPerB;
  int n = (u % tilesPerB) * 256 + threadIdx.x;
  for (int i = threadIdx.x; i < S; i += 256) {
    float xx = xyz2[((size_t)b * 3 + 0) * S + i];
    float yy = xyz2[((size_t)b * 3 + 1) * S + i];
    float zz = xyz2[((size_t)b * 3 + 2) * S + i];
    x2s[i] = xx; x2s[S + i] = yy; x2s[2 * S + i] = zz;
    n2s[i] = xx * xx + yy * yy + zz * zz;
  }
  __syncthreads();
  float X = xyz1[((size_t)b * 3 + 0) * Npts + n];
  float Y = xyz1[((size_t)b * 3 + 1) * Npts + n];
  float Z = xyz1[((size_t)b * 3 + 2) * Npts + n];
  float n1v = X * X + Y * Y + Z * Z;
  float d0 = 1e30f, d1 = 1e30f, d2 = 1e30f;
  int i0 = 0, i1 = 0, i2 = 0;
  for (int s = 0; s < S; s++) {
    float d = n1v + n2s[s] - 2.0f * (X * x2s[s] + Y * x2s[S + s] + Z * x2s[2 * S + s]);
    if (d < d0)      { d2 = d1; i2 = i1; d1 = d0; i1 = i0; d0 = d; i0 = s; }
    else if (d < d1) { d2 = d1; i2 = i1; d1 = d; i1 = s; }
    else if (d < d2) { d2 = d; i2 = s; }
  }
  float w0 = 1.0f / (d0 + 1e-8f), w1 = 1.0f / (d1 + 1e-8f), w2 = 1.0f / (d2 + 1e-8f);
  float wsum = w0 + w1 + w2;
  w0 /= wsum; w1 /= wsum; w2 /= wsum;
  const float* g0 = featT + ((size_t)b * S + i0) * C;
  const float* g1 = featT + ((size_t)b * S + i1) * C;
  const float* g2 = featT + ((size_t)b * S + i2) * C;
  if constexpr (C % 4 == 0) {
    const float4* v0 = (const float4*)g0;
    const float4* v1 = (const float4*)g1;
    const float4* v2 = (const float4*)g2;
#pragma unroll 4
    for (int c4 = 0; c4 < C / 4; c4++) {
      float4 a = v0[c4], bb = v1[c4], cc = v2[c4];
      float4 r;
      r.x = w0 * a.x + w1 * bb.x + w2 * cc.x;
      r.y = w0 * a.y + w1 * bb.y + w2 * cc.y;
      r.z = w0 * a.z + w1 * bb.z + w2 * cc.z;
      r.w = w0 * a.w + w1 * bb.w + w2 * cc.w;
      if constexpr (TOUT) {
        ((float4*)(out + ((size_t)b * Npts + n) * C))[c4] = r;
      } else {
        out[((size_t)b * C + 4 * c4 + 0) * Npts + n] = r.x;
        out[((size_t)b * C + 4 * c4 + 1) * Npts + n] = r.y;
        out[((size_t)b * C + 4 * c4 + 2) * Npts + n] = r.z;
        out[((size_t)b * C + 4 * c4 + 3) * Npts + n] = r.w;
      }
    }
  } else {
#pragma unroll
    for (int c = 0; c < C; c++) {
      float val = w0 * g0[c] + w1 * g1[c] + w2 * g2[c];
      if constexpr (TOUT) out[((size_t)b * Npts + n) * C + c] = val;
      else                out[((size_t)b * C + c) * Npts + n] = val;
    }
  }
}

// ---------------- launch 2: kNN (blocks < KB) || fprop_B (tail blocks) ----------------
__global__ void knn_fprop_kernel(const float* __restrict__ xyz_l2, const int* __restrict__ fps1,
                                 int* __restrict__ knn1,
                                 const float* __restrict__ xyz_l1, const int* __restrict__ fps2,
                                 int* __restrict__ knn2,
                                 const float* __restrict__ xyz_l3, const float* __restrict__ flow0,
                                 float* __restrict__ flow0_us) {
  __shared__ float sm[4 * N3C];
  const int KB = (NB * N2 + NB * N1) / 4;   // 3072
  int blk = blockIdx.x;
  if (blk < KB) {
    int gw = blk * 4 + (threadIdx.x >> 6);
    if (gw < NB * N2) knn_impl<N2, 8>(xyz_l2, fps1, knn1, gw);
    else              knn_impl<N1, 16>(xyz_l1, fps2, knn2, gw - NB * N2);
  } else {
    fprop_unit<3, true, N3C>(blk - KB, N2, xyz_l2, xyz_l3, flow0, flow0_us, sm);
  }
}

// ---------------- standalone fprop ----------------
template <int C, bool TOUT, int S>
__global__ void fprop_kernel(const float* __restrict__ xyz1, const float* __restrict__ xyz2,
                             const float* __restrict__ featT, float* __restrict__ out, int N) {
  __shared__ float sm[4 * S];
  fprop_unit<C, TOUT, S>(blockIdx.x, N, xyz1, xyz2, featT, out, sm);
}

// ---- per-wave partial {sum, sumsq} writer; blk = effective block idx, doff runtime ----
template <int D>
static __device__ __forceinline__ void write_partials(const float* acc, int b, int bpb, int blk,
                                                      int dtot, int doff,
                                                      float* __restrict__ ps, float* __restrict__ pq) {
  int lane = threadIdx.x & 63;
  int slot = (blk - b * bpb) * 4 + (threadIdx.x >> 6);
#pragma unroll
  for (int i = 0; i < D; i++) {
    float s = wave_sum63(acc[i]);
    float q = wave_sum63(acc[i] * acc[i]);
    if (lane == 63) {
      size_t row = (size_t)(b * dtot + doff + i) * PSTRIDE + slot;
      ps[row] = s; pq[row] = q;
    }
  }
}

// ---------------- layer-0 matmul + fused gather + partial stats (proven) ----------------
template <int CF, int D>
__global__ void mm0p_kernel(const float* __restrict__ xyz, const float* __restrict__ featsT,
                            const int* __restrict__ fps_idx, const int* __restrict__ knn,
                            const float* __restrict__ w, float* __restrict__ y,
                            float* __restrict__ ps, float* __restrict__ pq, int S) {
  const int SK = S * KNN;
  int t = blockIdx.x * 256 + threadIdx.x;
  int b = t / SK, sk = t % SK, s = sk / KNN;
  int nb = knn[(size_t)b * SK + sk];
  int ctr = fps_idx[(size_t)b * S + s];
  const float* xb = xyz + (size_t)b * 3 * S;
  float r0 = xb[nb] - xb[ctr];
  float r1 = xb[S + nb] - xb[S + ctr];
  float r2 = xb[2 * S + nb] - xb[2 * S + ctr];
  float acc[D];
#pragma unroll
  for (int i = 0; i < D; i++)
    acc[i] = fmaf(r0, w[i], fmaf(r1, w[D + i], r2 * w[2 * D + i]));
  const float* pb = featsT + ((size_t)b * S + nb) * CF;
  if constexpr (CF % 4 == 0) {
    const float4* pv = (const float4*)pb;
    for (int c4 = 0; c4 < CF / 4; c4++) {
      float4 v = pv[c4];
      const float* wr = w + (size_t)(3 + 4 * c4) * D;
#pragma unroll
      for (int i = 0; i < D; i++)
        acc[i] = fmaf(v.x, wr[i],
                 fmaf(v.y, wr[D + i],
                 fmaf(v.z, wr[2 * D + i],
                 fmaf(v.w, wr[3 * D + i], acc[i]))));
    }
  } else {
#pragma unroll
    for (int c = 0; c < CF; c++) {
      float xv = pb[c];
      const float* wr = w + (size_t)(3 + c) * D;
#pragma unroll
      for (int i = 0; i < D; i++) acc[i] = fmaf(xv, wr[i], acc[i]);
    }
  }
  float* yb = y + (size_t)b * D * SK + sk;
#pragma unroll
  for (int i = 0; i < D; i++) yb[(size_t)i * SK] = acc[i];
  write_partials<D>(acc, b, SK / 256, blockIdx.x, D, 0, ps, pq);
}

// ---- matmul + input-IN+relu, stats folded; grid may hold 2 D-halves (doff by block range) ----
template <int Cin, int D, int DTOT>
__global__ void mmnorms_kernel(const float* __restrict__ x, const float* __restrict__ w,
                               const float* __restrict__ ps_in, const float* __restrict__ pq_in,
                               const float* __restrict__ g, const float* __restrict__ beta,
                               float* __restrict__ y, float* __restrict__ ps_out,
                               float* __restrict__ pq_out, int SK, int G) {
  __shared__ float smean[Cin], srstd[Cin];
  const int NS = SK / 64;
  int blk = blockIdx.x;
  int doff = 0;
  if (blk >= G) { blk -= G; doff = D; }             // second D-half
  int b = (int)(((size_t)blk * 256) / SK);          // uniform per block (256 | SK)
  {
    const int TPC = 256 / Cin;                      // 8 (Cin=32) or 4 (Cin=64)
    int c = threadIdx.x / TPC, r = threadIdx.x % TPC;
    const float* p1 = ps_in + (size_t)(b * Cin + c) * PSTRIDE;
    const float* p2 = pq_in + (size_t)(b * Cin + c) * PSTRIDE;
    float s = 0.f, q = 0.f;
    for (int j = r; j < NS; j += TPC) { s += p1[j]; q += p2[j]; }
    for (int off = TPC / 2; off; off >>= 1) {       // group-aligned within wave
      s += __shfl_down(s, off, 64);
      q += __shfl_down(q, off, 64);
    }
    if (r == 0) {
      float mu = s / (float)SK;
      float var = q / (float)SK - mu * mu;
      smean[c] = mu;
      srstd[c] = 1.0f / sqrtf(var + 1e-5f);
    }
  }
  __syncthreads();
  int t = blk * 256 + threadIdx.x;
  int sk = t % SK;
  const float* xb = x + (size_t)b * Cin * SK + sk;
  float* yb = y + (size_t)b * DTOT * SK + sk;
  float acc[D];
#pragma unroll
  for (int i = 0; i < D; i++) acc[i] = 0.f;
  for (int c = 0; c < Cin; c++) {
    float sc = srstd[c] * g[c];
    float sh = fmaf(-smean[c], sc, beta[c]);
    float xv = fmaxf(fmaf(xb[(size_t)c * SK], sc, sh), 0.f);
    const float* wr = w + (size_t)c * DTOT + doff;
#pragma unroll
    for (int i = 0; i < D; i++) acc[i] = fmaf(xv, wr[i], acc[i]);
  }
#pragma unroll
  for (int i = 0; i < D; i++) yb[(size_t)(doff + i) * SK] = acc[i];
  write_partials<D>(acc, b, SK / 256, blk, DTOT, doff, ps_out, pq_out);
}

// ---------------- IN+relu+max-over-K, stats folded; one (b,d) row chunk per block ----------------
template <int D>
__global__ void maxpool_norms_kernel(const float* __restrict__ y, const float* __restrict__ ps,
                                     const float* __restrict__ pq, const float* __restrict__ g,
                                     const float* __restrict__ beta, float* __restrict__ outT,
                                     int S) {
  __shared__ float sred[8];
  const int SK = S * KNN;
  const int NS = SK / 64;
  int t = blockIdx.x * 256 + threadIdx.x;
  int s = t % S;
  int bd = t / S;                                   // uniform per block (256 | S)
  int d = bd % D, b = bd / D;
  float ssum = 0.f, qsum = 0.f;
  {
    const float* p1 = ps + (size_t)bd * PSTRIDE;
    const float* p2 = pq + (size_t)bd * PSTRIDE;
    for (int j = threadIdx.x; j < NS; j += 256) { ssum += p1[j]; qsum += p2[j]; }
    for (int off = 32; off; off >>= 1) { ssum += __shfl_xor(ssum, off, 64); qsum += __shfl_xor(qsum, off, 64); }
    int wid = threadIdx.x >> 6;
    if ((threadIdx.x & 63) == 0) { sred[wid] = ssum; sred[4 + wid] = qsum; }
    __syncthreads();
    ssum = sred[0] + sred[1] + sred[2] + sred[3];
    qsum = sred[4] + sred[5] + sred[6] + sred[7];
  }
  float mu = ssum / (float)SK;
  float var = qsum / (float)SK - mu * mu;
  float rstd = 1.0f / sqrtf(var + 1e-5f);
  float sc = rstd * g[d];
  float sh = fmaf(-mu, sc, beta[d]);
  const float4* p = (const float4*)(y + (size_t)t * KNN);
  float m = -1e30f;
#pragma unroll
  for (int q = 0; q < 4; q++) {
    float4 v = p[q];
    m = fmaxf(m, fmaf(v.x, sc, sh)); m = fmaxf(m, fmaf(v.y, sc, sh));
    m = fmaxf(m, fmaf(v.z, sc, sh)); m = fmaxf(m, fmaf(v.w, sc, sh));
  }
  outT[((size_t)b * S + s) * D + d] = fmaxf(m, 0.f);   // relu(max) == max(relu)
}

extern "C" void kernel_launch(void* const* d_in, const int* in_sizes, int n_in,
                              void* d_out, int out_size, void* d_ws, size_t ws_size,
                              hipStream_t stream) {
  const float* pc1_l0 = (const float*)d_in[0];
  const float* pc1_l1 = (const float*)d_in[1];
  const float* pc1_l2 = (const float*)d_in[2];
  const float* pc1_l3 = (const float*)d_in[3];
  const float* pc2_l3 = (const float*)d_in[4];
  const float* feats1 = (const float*)d_in[5];
  const float* feats2 = (const float*)d_in[6];
  const float* epsilon = (const float*)d_in[7];
  const float* sa1_w[3] = {(const float*)d_in[8], (const float*)d_in[9], (const float*)d_in[10]};
  const float* sa1_g[3] = {(const float*)d_in[11], (const float*)d_in[13], (const float*)d_in[15]};
  const float* sa1_b[3] = {(const float*)d_in[12], (const float*)d_in[14], (const float*)d_in[16]};
  const float* sa2_w[3] = {(const float*)d_in[17], (const float*)d_in[18], (const float*)d_in[19]};
  const float* sa2_g[3] = {(const float*)d_in[20], (const float*)d_in[22], (const float*)d_in[24]};
  const float* sa2_b[3] = {(const float*)d_in[21], (const float*)d_in[23], (const float*)d_in[25]};

  char* ws = (char*)d_ws;
  size_t off = 0;
  auto alloc = [&](size_t bytes) { char* p = ws + off; off += (bytes + 255) & ~(size_t)255; return p; };
  float* bigA     = (float*)alloc((size_t)NB * 128 * N1 * KNN * 4);  // 67.1MB
  float* bigB     = (float*)alloc((size_t)NB * 64 * N1 * KNN * 4);   // 33.6MB
  float* psA      = (float*)alloc((size_t)NB * 128 * PSTRIDE * 4);   // 1MB
  float* pqA      = (float*)alloc((size_t)NB * 128 * PSTRIDE * 4);
  float* psB      = (float*)alloc((size_t)NB * 128 * PSTRIDE * 4);
  float* pqB      = (float*)alloc((size_t)NB * 128 * PSTRIDE * 4);
  float* flow0    = (float*)alloc((size_t)NB * N3C * 3 * 4);
  float* flow0_us = (float*)alloc((size_t)NB * N2 * 3 * 4);
  int*   fps1     = (int*)alloc((size_t)NB * N2 * 4);
  int*   knn1     = (int*)alloc((size_t)NB * N2 * KNN * 4);
  float* cf2      = (float*)alloc((size_t)NB * N2 * 64 * 4);
  float* cf1a     = (float*)alloc((size_t)NB * N1 * 64 * 4);
  int*   fps2     = (int*)alloc((size_t)NB * N1 * 4);
  int*   knn2     = (int*)alloc((size_t)NB * N1 * KNN * 4);
  float* cf1b     = (float*)alloc((size_t)NB * N1 * 128 * 4);
  (void)ws_size; (void)in_sizes; (void)n_in; (void)out_size;

  // ---- 1: FPS (4-wave coop, v3 register-coord publish) || correlation flow ----
  fps_corr_kernel<<<2 * NB + 2048, 256, 0, stream>>>(pc1_l2, pc1_l1, fps1, fps2,
                                                     feats1, feats2, pc1_l3, pc2_l3,
                                                     epsilon, flow0);

  // ---- 2: kNN || flow upsample 256->512 ----
  knn_fprop_kernel<<<(NB * N2 + NB * N1) / 4 + NB * (N2 / 256), 256, 0, stream>>>(
      pc1_l2, fps1, knn1, pc1_l1, fps2, knn2, pc1_l3, flow0, flow0_us);

  // ---- SA1 (S=512): 6->32->32->64 ----
  {
    const int S = N2, SK = S * KNN;
    const int G = NB * SK / 256;
    mm0p_kernel<3, 32><<<G, 256, 0, stream>>>(pc1_l2, flow0_us, fps1, knn1, sa1_w[0],
                                              bigA, psA, pqA, S);
    mmnorms_kernel<32, 32, 32><<<G, 256, 0, stream>>>(bigA, sa1_w[1], psA, pqA,
                                                      sa1_g[0], sa1_b[0],
                                                      bigB, psB, pqB, SK, G);
    mmnorms_kernel<32, 64, 64><<<G, 256, 0, stream>>>(bigB, sa1_w[2], psB, pqB,
                                                      sa1_g[1], sa1_b[1],
                                                      bigA, psA, pqA, SK, G);
    maxpool_norms_kernel<64><<<NB * 64 * S / 256, 256, 0, stream>>>(bigA, psA, pqA,
                                                                    sa1_g[2], sa1_b[2], cf2, S);
  }

  // ---- propagate 512 -> 1024 ----
  fprop_kernel<64, true, N2><<<NB * (N1 / 256), 256, 0, stream>>>(pc1_l1, pc1_l2, cf2, cf1a, N1);

  // ---- SA2 (S=1024): 67->64->64->128 ----
  {
    const int S = N1, SK = S * KNN;
    const int G = NB * SK / 256;
    mm0p_kernel<64, 64><<<G, 256, 0, stream>>>(pc1_l1, cf1a, fps2, knn2, sa2_w[0],
                                               bigA, psA, pqA, S);
    mmnorms_kernel<64, 64, 64><<<G, 256, 0, stream>>>(bigA, sa2_w[1], psA, pqA,
                                                      sa2_g[0], sa2_b[0],
                                                      bigB, psB, pqB, SK, G);
    // D=128 as two halves in ONE launch (blocks [0,G) -> doff 0, [G,2G) -> doff 64)
    mmnorms_kernel<64, 64, 128><<<2 * G, 256, 0, stream>>>(bigB, sa2_w[2], psB, pqB,
                                                           sa2_g[1], sa2_b[1],
                                                           bigA, psA, pqA, SK, G);
    maxpool_norms_kernel<128><<<NB * 128 * S / 256, 256, 0, stream>>>(bigA, psA, pqA,
                                                                      sa2_g[2], sa2_b[2], cf1b, S);
  }

  // ---- final propagate 1024 -> 8192 into d_out ----
  fprop_kernel<128, false, N1><<<NB * (N0 / 256), 256, 0, stream>>>(pc1_l0, pc1_l1, cf1b,
                                                                    (float*)d_out, N0);
}

// Round 14
// 825.142 us; speedup vs baseline: 1.1676x; 1.1676x over previous
//
#include <hip/hip_runtime.h>
#include <math.h>

#define NB 8
#define N0 8192
#define N1 1024
#define N2 512
#define N3C 256
#define CFEAT 256
#define KNN 16
#define PSTRIDE 256   // max partial slots per (b,d) row (NS <= 256)

typedef float v2f __attribute__((ext_vector_type(2)));

static __device__ __forceinline__ v2f pk_add(v2f a, v2f b) {
  v2f r; asm("v_pk_add_f32 %0, %1, %2" : "=v"(r) : "v"(a), "v"(b)); return r;
}
static __device__ __forceinline__ v2f pk_mul(v2f a, v2f b) {
  v2f r; asm("v_pk_mul_f32 %0, %1, %2" : "=v"(r) : "v"(a), "v"(b)); return r;
}

// ---- f64-key DPP wave64 max (bound_ctrl=false safe: max idempotent) ----
template <int CTRL, int RM>
static __device__ __forceinline__ double dpp_fmax64(double m) {
  int mh = __double2hiint(m), ml = __double2loint(m);
  int ch = __builtin_amdgcn_update_dpp(mh, mh, CTRL, RM, 0xF, false);
  int cl = __builtin_amdgcn_update_dpp(ml, ml, CTRL, RM, 0xF, false);
  return fmax(m, __hiloint2double(ch, cl));
}
static __device__ __forceinline__ double wave_fmax64(double m) {
  m = dpp_fmax64<0x111, 0xF>(m);
  m = dpp_fmax64<0x112, 0xF>(m);
  m = dpp_fmax64<0x114, 0xF>(m);
  m = dpp_fmax64<0x118, 0xF>(m);
  m = dpp_fmax64<0x142, 0xA>(m);
  m = dpp_fmax64<0x143, 0xC>(m);   // lane 63 complete
  return m;
}

// ---- (key,idx) u64 DPP min for kNN (proven) ----
template <int CTRL, int RM>
static __device__ __forceinline__ void dpp_minstep(uint32_t& hi, uint32_t& lo) {
  uint32_t chi = (uint32_t)__builtin_amdgcn_update_dpp((int)hi, (int)hi, CTRL, RM, 0xF, false);
  uint32_t clo = (uint32_t)__builtin_amdgcn_update_dpp((int)lo, (int)lo, CTRL, RM, 0xF, false);
  unsigned long long cand = ((unsigned long long)chi << 32) | clo;
  unsigned long long cur  = ((unsigned long long)hi  << 32) | lo;
  if (cand < cur) { hi = chi; lo = clo; }
}
static __device__ __forceinline__ void wave_min_pair(uint32_t& hi, uint32_t& lo) {
  dpp_minstep<0x111, 0xF>(hi, lo);
  dpp_minstep<0x112, 0xF>(hi, lo);
  dpp_minstep<0x114, 0xF>(hi, lo);
  dpp_minstep<0x118, 0xF>(hi, lo);
  dpp_minstep<0x142, 0xA>(hi, lo);
  dpp_minstep<0x143, 0xC>(hi, lo);
}

// ---- DPP wave64 f32 SUM: bound_ctrl=TRUE (invalid lanes contribute 0) ----
template <int CTRL, int RM>
static __device__ __forceinline__ float dpp_addstep(float x) {
  int xi = __float_as_int(x);
  int sv = __builtin_amdgcn_update_dpp(xi, xi, CTRL, RM, 0xF, true);
  return x + __int_as_float(sv);
}
static __device__ __forceinline__ float wave_sum63(float x) {
  x = dpp_addstep<0x111, 0xF>(x);
  x = dpp_addstep<0x112, 0xF>(x);
  x = dpp_addstep<0x114, 0xF>(x);
  x = dpp_addstep<0x118, 0xF>(x);
  x = dpp_addstep<0x142, 0xA>(x);
  x = dpp_addstep<0x143, 0xC>(x);
  return x;   // lane 63 = wave sum
}

// ---------------- 4-wave cooperative FPS scan (R11-proven; uniform sm[far] broadcast) ----------------
// Wave w owns contiguous [w*N/4, (w+1)*N/4); lane owns PPW consecutive points.
// Keys {hi=dist_bits, lo=~idx} unique -> max order-free; ~idx = lowest-idx ties.
template <int N>
static __device__ void fps_scan4(const float4* sm, double* kb, int* idx_out) {
  constexpr int PPW = N / 256;        // 2 (N2) or 4 (N1)
  int tid = threadIdx.x;
  int lane = tid & 63;
  int w = tid >> 6;
  int base = w * (N / 4) + lane * PPW;
  v2f px[PPW / 2], py[PPW / 2], pz[PPW / 2];
  float dist[PPW];
  int nlo[PPW];
#pragma unroll
  for (int k = 0; k < PPW / 2; k++) {
    float4 a = sm[base + 2 * k];
    float4 c = sm[base + 2 * k + 1];
    px[k] = v2f{a.x, c.x}; py[k] = v2f{a.y, c.y}; pz[k] = v2f{a.z, c.z};
    dist[2 * k] = 1e10f; dist[2 * k + 1] = 1e10f;
    nlo[2 * k] = ~(base + 2 * k); nlo[2 * k + 1] = ~(base + 2 * k + 1);
  }
  int far = 0;
  float4 f = sm[0];
  for (int t = 0; t < N; t++) {
    if (tid == 0) idx_out[t] = far;           // scan emits carry BEFORE update
    v2f vfx = v2f{-f.x, -f.x}, vfy = v2f{-f.y, -f.y}, vfz = v2f{-f.z, -f.z};
#pragma unroll
    for (int k = 0; k < PPW / 2; k++) {       // x+(-y)==x-y exactly; pk rn per comp
      v2f dx = pk_add(px[k], vfx);
      v2f dy = pk_add(py[k], vfy);
      v2f dz = pk_add(pz[k], vfz);
      v2f dd = pk_add(pk_add(pk_mul(dx, dx), pk_mul(dy, dy)), pk_mul(dz, dz));
      dist[2 * k]     = fminf(dist[2 * k],     dd.x);
      dist[2 * k + 1] = fminf(dist[2 * k + 1], dd.y);
    }
    double tv[PPW / 2];
#pragma unroll
    for (int i = 0; i < PPW / 2; i++)
      tv[i] = fmax(__hiloint2double(__float_as_int(dist[2 * i]),     nlo[2 * i]),
                   __hiloint2double(__float_as_int(dist[2 * i + 1]), nlo[2 * i + 1]));
#pragma unroll
    for (int s = PPW / 4; s >= 1; s >>= 1)
#pragma unroll
      for (int i = 0; i < s; i++) tv[i] = fmax(tv[i], tv[i + s]);
    double m = wave_fmax64(tv[0]);
    if (lane == 63) kb[(t & 1) * 4 + w] = m;  // double-buffered: single barrier/iter
    __syncthreads();
    const double* kq = kb + (t & 1) * 4;
    double M = fmax(fmax(kq[0], kq[1]), fmax(kq[2], kq[3]));
    far = ~__double2loint(M);
    f = sm[far];                              // uniform LDS broadcast (conflict-free)
  }
}

// ---------------- corr unit (proven) ----------------
static __device__ void corr_unit(int u, const float* __restrict__ f1, const float* __restrict__ f2,
                                 const float* __restrict__ p1, const float* __restrict__ p2,
                                 const float* __restrict__ eps_in, float* __restrict__ flow0,
                                 char* smem) {
  float* f1c = (float*)smem;
  float* red = f1c + 256;
  float* p1s = red + 16;
  int b = u / N3C, n = u % N3C;
  int m = threadIdx.x;
  f1c[m] = f1[((size_t)b * CFEAT + m) * N3C + n];
  if (m < 3) p1s[m] = p1[((size_t)b * 3 + m) * N3C + n];
  __syncthreads();
  float eps = expf(eps_in[0]) + 0.03f;
  const float* f2b = f2 + (size_t)b * CFEAT * N3C;
  float dot = 0.f, s1 = 0.f, s2 = 0.f;
  for (int c = 0; c < CFEAT; c++) {
    float a = f1c[c];
    float v = f2b[(size_t)c * N3C + m];
    dot += a * v; s1 += a * a; s2 += v * v;
  }
  float rn1 = 1.0f / sqrtf(s1 + 1e-8f);
  float rn2 = 1.0f / sqrtf(s2 + 1e-8f);
  float Cv = 1.0f - dot * rn1 * rn2;
  float p2x = p2[((size_t)b * 3 + 0) * N3C + m];
  float p2y = p2[((size_t)b * 3 + 1) * N3C + m];
  float p2z = p2[((size_t)b * 3 + 2) * N3C + m];
  float n1v = p1s[0] * p1s[0] + p1s[1] * p1s[1] + p1s[2] * p1s[2];
  float n2v = p2x * p2x + p2y * p2y + p2z * p2z;
  float dd = n1v + n2v - 2.0f * (p1s[0] * p2x + p1s[1] * p2y + p1s[2] * p2z);
  float corr = (dd < 100.0f) ? expf(-Cv / eps) : 0.0f;
  float s0 = corr, t1 = corr * p2x, t2 = corr * p2y, t3 = corr * p2z;
  for (int off = 32; off; off >>= 1) {
    s0 += __shfl_xor(s0, off, 64); t1 += __shfl_xor(t1, off, 64);
    t2 += __shfl_xor(t2, off, 64); t3 += __shfl_xor(t3, off, 64);
  }
  int wid = threadIdx.x >> 6;
  if ((threadIdx.x & 63) == 0) { red[wid] = s0; red[4 + wid] = t1; red[8 + wid] = t2; red[12 + wid] = t3; }
  __syncthreads();
  if (threadIdx.x == 0) {
    float r0 = red[0] + red[1] + red[2] + red[3];
    float r1 = red[4] + red[5] + red[6] + red[7];
    float r2 = red[8] + red[9] + red[10] + red[11];
    float r3 = red[12] + red[13] + red[14] + red[15];
    float inv = 1.0f / (r0 + 1e-8f);
    float* fo = flow0 + ((size_t)b * N3C + n) * 3;
    fo[0] = r1 * inv - p1s[0];
    fo[1] = r2 * inv - p1s[1];
    fo[2] = r3 * inv - p1s[2];
  }
  __syncthreads();
}

// ---------------- launch 1: FPS (blocks 0..15, 4-wave) || corr (blocks 16+) ----------------
__global__ void fps_corr_kernel(const float* __restrict__ xyz_l2, const float* __restrict__ xyz_l1,
                                int* __restrict__ fps1, int* __restrict__ fps2,
                                const float* __restrict__ f1, const float* __restrict__ f2,
                                const float* __restrict__ p1, const float* __restrict__ p2,
                                const float* __restrict__ eps_in, float* __restrict__ flow0) {
  __shared__ __align__(16) char smem[16448];
  int blk = blockIdx.x, tid = threadIdx.x;
  if (blk < 2 * NB) {
    float4* sm = (float4*)smem;
    double* kb = (double*)(smem + 16384);
    if (blk < NB) {
      const float* xb = xyz_l2 + (size_t)blk * 3 * N2;
      for (int i = tid; i < N2; i += 256) {
        float4 v; v.x = xb[i]; v.y = xb[N2 + i]; v.z = xb[2 * N2 + i]; v.w = 0.f;
        sm[i] = v;
      }
      __syncthreads();
      fps_scan4<N2>(sm, kb, fps1 + (size_t)blk * N2);
    } else {
      int b = blk - NB;
      const float* xb = xyz_l1 + (size_t)b * 3 * N1;
      for (int i = tid; i < N1; i += 256) {
        float4 v; v.x = xb[i]; v.y = xb[N1 + i]; v.z = xb[2 * N1 + i]; v.w = 0.f;
        sm[i] = v;
      }
      __syncthreads();
      fps_scan4<N1>(sm, kb, fps2 + (size_t)b * N1);
    }
  } else {
    for (int u = blk - 2 * NB; u < NB * N3C; u += (int)gridDim.x - 2 * NB)
      corr_unit(u, f1, f2, p1, p2, eps_in, flow0, smem);
  }
}

// ---------------- kNN (proven) ----------------
template <int S, int PPL>
static __device__ void knn_impl(const float* __restrict__ xyz, const int* __restrict__ fps_idx,
                                int* __restrict__ knn_out, int gw) {
  int lane = threadIdx.x & 63;
  int b = gw / S, s = gw % S;
  int center = fps_idx[(size_t)b * S + s];
  const float* xb = xyz + (size_t)b * 3 * S;
  float cx = xb[center], cy = xb[S + center], cz = xb[2 * S + center];
  float cn = cx * cx + cy * cy + cz * cz;
  uint32_t kb[PPL];
#pragma unroll
  for (int j = 0; j < PPL; j++) {
    int g = lane * PPL + j;
    float x = xb[g], y = xb[S + g], z = xb[2 * S + g];
    float pn = x * x + y * y + z * z;
    float d = cn + pn - 2.0f * (cx * x + cy * y + cz * z);
    uint32_t bts = __float_as_uint(d);
    kb[j] = bts ^ ((uint32_t)((int)bts >> 31) | 0x80000000u);
  }
  int* ob = knn_out + ((size_t)b * S + s) * KNN;
  for (int r = 0; r < KNN; r++) {
    uint32_t bh = 0xFFFFFFFFu, bl = 0xFFFFFFFFu;
#pragma unroll
    for (int j = 0; j < PPL; j++) {
      unsigned long long cand = ((unsigned long long)kb[j] << 32) | (uint32_t)(lane * PPL + j);
      unsigned long long cur  = ((unsigned long long)bh << 32) | bl;
      if (cand < cur) { bh = kb[j]; bl = (uint32_t)(lane * PPL + j); }
    }
    wave_min_pair(bh, bl);
    uint32_t widx = (uint32_t)__builtin_amdgcn_readlane((int)bl, 63);
    if (lane == 0) ob[r] = (int)widx;
#pragma unroll
    for (int j = 0; j < PPL; j++)
      if ((uint32_t)(lane * PPL + j) == widx) kb[j] = 0xFFFFFFFFu;
  }
}

// ---------------- 3-NN interpolation unit (proven) ----------------
template <int C, bool TOUT, int S>
static __device__ void fprop_unit(int u, int Npts, const float* __restrict__ xyz1,
                                  const float* __restrict__ xyz2, const float* __restrict__ featT,
                                  float* __restrict__ out, float* smem) {
  float* x2s = smem;
  float* n2s = x2s + 3 * S;
  int tilesPerB = Npts / 256;
  int b = u / tilesPerB;
  int n = (u % tilesPerB) * 256 + threadIdx.x;
  for (int i = threadIdx.x; i < S; i += 256) {
    float xx = xyz2[((size_t)b * 3 + 0) * S + i];
    float yy = xyz2[((size_t)b * 3 + 1) * S + i];
    float zz = xyz2[((size_t)b * 3 + 2) * S + i];
    x2s[i] = xx; x2s[S + i] = yy; x2s[2 * S + i] = zz;
    n2s[i] = xx * xx + yy * yy + zz * zz;
  }
  __syncthreads();
  float X = xyz1[((size_t)b * 3 + 0) * Npts + n];
  float Y = xyz1[((size_t)b * 3 + 1) * Npts + n];
  float Z = xyz1[((size_t)b * 3 + 2) * Npts + n];
  float n1v = X * X + Y * Y + Z * Z;
  float d0 = 1e30f, d1 = 1e30f, d2 = 1e30f;
  int i0 = 0, i1 = 0, i2 = 0;
  for (int s = 0; s < S; s++) {
    float d = n1v + n2s[s] - 2.0f * (X * x2s[s] + Y * x2s[S + s] + Z * x2s[2 * S + s]);
    if (d < d0)      { d2 = d1; i2 = i1; d1 = d0; i1 = i0; d0 = d; i0 = s; }
    else if (d < d1) { d2 = d1; i2 = i1; d1 = d; i1 = s; }
    else if (d < d2) { d2 = d; i2 = s; }
  }
  float w0 = 1.0f / (d0 + 1e-8f), w1 = 1.0f / (d1 + 1e-8f), w2 = 1.0f / (d2 + 1e-8f);
  float wsum = w0 + w1 + w2;
  w0 /= wsum; w1 /= wsum; w2 /= wsum;
  const float* g0 = featT + ((size_t)b * S + i0) * C;
  const float* g1 = featT + ((size_t)b * S + i1) * C;
  const float* g2 = featT + ((size_t)b * S + i2) * C;
  if constexpr (C % 4 == 0) {
    const float4* v0 = (const float4*)g0;
    const float4* v1 = (const float4*)g1;
    const float4* v2 = (const float4*)g2;
#pragma unroll 4
    for (int c4 = 0; c4 < C / 4; c4++) {
      float4 a = v0[c4], bb = v1[c4], cc = v2[c4];
      float4 r;
      r.x = w0 * a.x + w1 * bb.x + w2 * cc.x;
      r.y = w0 * a.y + w1 * bb.y + w2 * cc.y;
      r.z = w0 * a.z + w1 * bb.z + w2 * cc.z;
      r.w = w0 * a.w + w1 * bb.w + w2 * cc.w;
      if constexpr (TOUT) {
        ((float4*)(out + ((size_t)b * Npts + n) * C))[c4] = r;
      } else {
        out[((size_t)b * C + 4 * c4 + 0) * Npts + n] = r.x;
        out[((size_t)b * C + 4 * c4 + 1) * Npts + n] = r.y;
        out[((size_t)b * C + 4 * c4 + 2) * Npts + n] = r.z;
        out[((size_t)b * C + 4 * c4 + 3) * Npts + n] = r.w;
      }
    }
  } else {
#pragma unroll
    for (int c = 0; c < C; c++) {
      float val = w0 * g0[c] + w1 * g1[c] + w2 * g2[c];
      if constexpr (TOUT) out[((size_t)b * Npts + n) * C + c] = val;
      else                out[((size_t)b * C + c) * Npts + n] = val;
    }
  }
}

// ---------------- launch 2: kNN (blocks < KB) || fprop_B (tail blocks) ----------------
__global__ void knn_fprop_kernel(const float* __restrict__ xyz_l2, const int* __restrict__ fps1,
                                 int* __restrict__ knn1,
                                 const float* __restrict__ xyz_l1, const int* __restrict__ fps2,
                                 int* __restrict__ knn2,
                                 const float* __restrict__ xyz_l3, const float* __restrict__ flow0,
                                 float* __restrict__ flow0_us) {
  __shared__ float sm[4 * N3C];
  const int KB = (NB * N2 + NB * N1) / 4;   // 3072
  int blk = blockIdx.x;
  if (blk < KB) {
    int gw = blk * 4 + (threadIdx.x >> 6);
    if (gw < NB * N2) knn_impl<N2, 8>(xyz_l2, fps1, knn1, gw);
    else              knn_impl<N1, 16>(xyz_l1, fps2, knn2, gw - NB * N2);
  } else {
    fprop_unit<3, true, N3C>(blk - KB, N2, xyz_l2, xyz_l3, flow0, flow0_us, sm);
  }
}

// ---------------- standalone fprop ----------------
template <int C, bool TOUT, int S>
__global__ void fprop_kernel(const float* __restrict__ xyz1, const float* __restrict__ xyz2,
                             const float* __restrict__ featT, float* __restrict__ out, int N) {
  __shared__ float sm[4 * S];
  fprop_unit<C, TOUT, S>(blockIdx.x, N, xyz1, xyz2, featT, out, sm);
}

// ---- per-wave partial {sum, sumsq} writer; blk = effective block idx, doff runtime ----
template <int D>
static __device__ __forceinline__ void write_partials(const float* acc, int b, int bpb, int blk,
                                                      int dtot, int doff,
                                                      float* __restrict__ ps, float* __restrict__ pq) {
  int lane = threadIdx.x & 63;
  int slot = (blk - b * bpb) * 4 + (threadIdx.x >> 6);
#pragma unroll
  for (int i = 0; i < D; i++) {
    float s = wave_sum63(acc[i]);
    float q = wave_sum63(acc[i] * acc[i]);
    if (lane == 63) {
      size_t row = (size_t)(b * dtot + doff + i) * PSTRIDE + slot;
      ps[row] = s; pq[row] = q;
    }
  }
}

// ---------------- layer-0 matmul + fused gather + partial stats (proven) ----------------
template <int CF, int D>
__global__ void mm0p_kernel(const float* __restrict__ xyz, const float* __restrict__ featsT,
                            const int* __restrict__ fps_idx, const int* __restrict__ knn,
                            const float* __restrict__ w, float* __restrict__ y,
                            float* __restrict__ ps, float* __restrict__ pq, int S) {
  const int SK = S * KNN;
  int t = blockIdx.x * 256 + threadIdx.x;
  int b = t / SK, sk = t % SK, s = sk / KNN;
  int nb = knn[(size_t)b * SK + sk];
  int ctr = fps_idx[(size_t)b * S + s];
  const float* xb = xyz + (size_t)b * 3 * S;
  float r0 = xb[nb] - xb[ctr];
  float r1 = xb[S + nb] - xb[S + ctr];
  float r2 = xb[2 * S + nb] - xb[2 * S + ctr];
  float acc[D];
#pragma unroll
  for (int i = 0; i < D; i++)
    acc[i] = fmaf(r0, w[i], fmaf(r1, w[D + i], r2 * w[2 * D + i]));
  const float* pb = featsT + ((size_t)b * S + nb) * CF;
  if constexpr (CF % 4 == 0) {
    const float4* pv = (const float4*)pb;
    for (int c4 = 0; c4 < CF / 4; c4++) {
      float4 v = pv[c4];
      const float* wr = w + (size_t)(3 + 4 * c4) * D;
#pragma unroll
      for (int i = 0; i < D; i++)
        acc[i] = fmaf(v.x, wr[i],
                 fmaf(v.y, wr[D + i],
                 fmaf(v.z, wr[2 * D + i],
                 fmaf(v.w, wr[3 * D + i], acc[i]))));
    }
  } else {
#pragma unroll
    for (int c = 0; c < CF; c++) {
      float xv = pb[c];
      const float* wr = w + (size_t)(3 + c) * D;
#pragma unroll
      for (int i = 0; i < D; i++) acc[i] = fmaf(xv, wr[i], acc[i]);
    }
  }
  float* yb = y + (size_t)b * D * SK + sk;
#pragma unroll
  for (int i = 0; i < D; i++) yb[(size_t)i * SK] = acc[i];
  write_partials<D>(acc, b, SK / 256, blockIdx.x, D, 0, ps, pq);
}

// ---- matmul + input-IN+relu, stats folded; grid may hold 2 D-halves (doff by block range) ----
template <int Cin, int D, int DTOT>
__global__ void mmnorms_kernel(const float* __restrict__ x, const float* __restrict__ w,
                               const float* __restrict__ ps_in, const float* __restrict__ pq_in,
                               const float* __restrict__ g, const float* __restrict__ beta,
                               float* __restrict__ y, float* __restrict__ ps_out,
                               float* __restrict__ pq_out, int SK, int G) {
  __shared__ float smean[Cin], srstd[Cin];
  const int NS = SK / 64;
  int blk = blockIdx.x;
  int doff = 0;
  if (blk >= G) { blk -= G; doff = D; }             // second D-half
  int b = (int)(((size_t)blk * 256) / SK);          // uniform per block (256 | SK)
  {
    const int TPC = 256 / Cin;                      // 8 (Cin=32) or 4 (Cin=64)
    int c = threadIdx.x / TPC, r = threadIdx.x % TPC;
    const float* p1 = ps_in + (size_t)(b * Cin + c) * PSTRIDE;
    const float* p2 = pq_in + (size_t)(b * Cin + c) * PSTRIDE;
    float s = 0.f, q = 0.f;
    for (int j = r; j < NS; j += TPC) { s += p1[j]; q += p2[j]; }
    for (int off = TPC / 2; off; off >>= 1) {       // group-aligned within wave
      s += __shfl_down(s, off, 64);
      q += __shfl_down(q, off, 64);
    }
    if (r == 0) {
      float mu = s / (float)SK;
      float var = q / (float)SK - mu * mu;
      smean[c] = mu;
      srstd[c] = 1.0f / sqrtf(var + 1e-5f);
    }
  }
  __syncthreads();
  int t = blk * 256 + threadIdx.x;
  int sk = t % SK;
  const float* xb = x + (size_t)b * Cin * SK + sk;
  float* yb = y + (size_t)b * DTOT * SK + sk;
  float acc[D];
#pragma unroll
  for (int i = 0; i < D; i++) acc[i] = 0.f;
  for (int c = 0; c < Cin; c++) {
    float sc = srstd[c] * g[c];
    float sh = fmaf(-smean[c], sc, beta[c]);
    float xv = fmaxf(fmaf(xb[(size_t)c * SK], sc, sh), 0.f);
    const float* wr = w + (size_t)c * DTOT + doff;
#pragma unroll
    for (int i = 0; i < D; i++) acc[i] = fmaf(xv, wr[i], acc[i]);
  }
#pragma unroll
  for (int i = 0; i < D; i++) yb[(size_t)(doff + i) * SK] = acc[i];
  write_partials<D>(acc, b, SK / 256, blk, DTOT, doff, ps_out, pq_out);
}

// ---------------- IN+relu+max-over-K, stats folded; one (b,d) row chunk per block ----------------
template <int D>
__global__ void maxpool_norms_kernel(const float* __restrict__ y, const float* __restrict__ ps,
                                     const float* __restrict__ pq, const float* __restrict__ g,
                                     const float* __restrict__ beta, float* __restrict__ outT,
                                     int S) {
  __shared__ float sred[8];
  const int SK = S * KNN;
  const int NS = SK / 64;
  int t = blockIdx.x * 256 + threadIdx.x;
  int s = t % S;
  int bd = t / S;                                   // uniform per block (256 | S)
  int d = bd % D, b = bd / D;
  float ssum = 0.f, qsum = 0.f;
  {
    const float* p1 = ps + (size_t)bd * PSTRIDE;
    const float* p2 = pq + (size_t)bd * PSTRIDE;
    for (int j = threadIdx.x; j < NS; j += 256) { ssum += p1[j]; qsum += p2[j]; }
    for (int off = 32; off; off >>= 1) { ssum += __shfl_xor(ssum, off, 64); qsum += __shfl_xor(qsum, off, 64); }
    int wid = threadIdx.x >> 6;
    if ((threadIdx.x & 63) == 0) { sred[wid] = ssum; sred[4 + wid] = qsum; }
    __syncthreads();
    ssum = sred[0] + sred[1] + sred[2] + sred[3];
    qsum = sred[4] + sred[5] + sred[6] + sred[7];
  }
  float mu = ssum / (float)SK;
  float var = qsum / (float)SK - mu * mu;
  float rstd = 1.0f / sqrtf(var + 1e-5f);
  float sc = rstd * g[d];
  float sh = fmaf(-mu, sc, beta[d]);
  const float4* p = (const float4*)(y + (size_t)t * KNN);
  float m = -1e30f;
#pragma unroll
  for (int q = 0; q < 4; q++) {
    float4 v = p[q];
    m = fmaxf(m, fmaf(v.x, sc, sh)); m = fmaxf(m, fmaf(v.y, sc, sh));
    m = fmaxf(m, fmaf(v.z, sc, sh)); m = fmaxf(m, fmaf(v.w, sc, sh));
  }
  outT[((size_t)b * S + s) * D + d] = fmaxf(m, 0.f);   // relu(max) == max(relu)
}

extern "C" void kernel_launch(void* const* d_in, const int* in_sizes, int n_in,
                              void* d_out, int out_size, void* d_ws, size_t ws_size,
                              hipStream_t stream) {
  const float* pc1_l0 = (const float*)d_in[0];
  const float* pc1_l1 = (const float*)d_in[1];
  const float* pc1_l2 = (const float*)d_in[2];
  const float* pc1_l3 = (const float*)d_in[3];
  const float* pc2_l3 = (const float*)d_in[4];
  const float* feats1 = (const float*)d_in[5];
  const float* feats2 = (const float*)d_in[6];
  const float* epsilon = (const float*)d_in[7];
  const float* sa1_w[3] = {(const float*)d_in[8], (const float*)d_in[9], (const float*)d_in[10]};
  const float* sa1_g[3] = {(const float*)d_in[11], (const float*)d_in[13], (const float*)d_in[15]};
  const float* sa1_b[3] = {(const float*)d_in[12], (const float*)d_in[14], (const float*)d_in[16]};
  const float* sa2_w[3] = {(const float*)d_in[17], (const float*)d_in[18], (const float*)d_in[19]};
  const float* sa2_g[3] = {(const float*)d_in[20], (const float*)d_in[22], (const float*)d_in[24]};
  const float* sa2_b[3] = {(const float*)d_in[21], (const float*)d_in[23], (const float*)d_in[25]};

  char* ws = (char*)d_ws;
  size_t off = 0;
  auto alloc = [&](size_t bytes) { char* p = ws + off; off += (bytes + 255) & ~(size_t)255; return p; };
  float* bigA     = (float*)alloc((size_t)NB * 128 * N1 * KNN * 4);  // 67.1MB
  float* bigB     = (float*)alloc((size_t)NB * 64 * N1 * KNN * 4);   // 33.6MB
  float* psA      = (float*)alloc((size_t)NB * 128 * PSTRIDE * 4);   // 1MB
  float* pqA      = (float*)alloc((size_t)NB * 128 * PSTRIDE * 4);
  float* psB      = (float*)alloc((size_t)NB * 128 * PSTRIDE * 4);
  float* pqB      = (float*)alloc((size_t)NB * 128 * PSTRIDE * 4);
  float* flow0    = (float*)alloc((size_t)NB * N3C * 3 * 4);
  float* flow0_us = (float*)alloc((size_t)NB * N2 * 3 * 4);
  int*   fps1     = (int*)alloc((size_t)NB * N2 * 4);
  int*   knn1     = (int*)alloc((size_t)NB * N2 * KNN * 4);
  float* cf2      = (float*)alloc((size_t)NB * N2 * 64 * 4);
  float* cf1a     = (float*)alloc((size_t)NB * N1 * 64 * 4);
  int*   fps2     = (int*)alloc((size_t)NB * N1 * 4);
  int*   knn2     = (int*)alloc((size_t)NB * N1 * KNN * 4);
  float* cf1b     = (float*)alloc((size_t)NB * N1 * 128 * 4);
  (void)ws_size; (void)in_sizes; (void)n_in; (void)out_size;

  // ---- 1: FPS (4-wave coop, R11-proven) || correlation flow ----
  fps_corr_kernel<<<2 * NB + 2048, 256, 0, stream>>>(pc1_l2, pc1_l1, fps1, fps2,
                                                     feats1, feats2, pc1_l3, pc2_l3,
                                                     epsilon, flow0);

  // ---- 2: kNN || flow upsample 256->512 ----
  knn_fprop_kernel<<<(NB * N2 + NB * N1) / 4 + NB * (N2 / 256), 256, 0, stream>>>(
      pc1_l2, fps1, knn1, pc1_l1, fps2, knn2, pc1_l3, flow0, flow0_us);

  // ---- SA1 (S=512): 6->32->32->64 ----
  {
    const int S = N2, SK = S * KNN;
    const int G = NB * SK / 256;
    mm0p_kernel<3, 32><<<G, 256, 0, stream>>>(pc1_l2, flow0_us, fps1, knn1, sa1_w[0],
                                              bigA, psA, pqA, S);
    mmnorms_kernel<32, 32, 32><<<G, 256, 0, stream>>>(bigA, sa1_w[1], psA, pqA,
                                                      sa1_g[0], sa1_b[0],
                                                      bigB, psB, pqB, SK, G);
    mmnorms_kernel<32, 64, 64><<<G, 256, 0, stream>>>(bigB, sa1_w[2], psB, pqB,
                                                      sa1_g[1], sa1_b[1],
                                                      bigA, psA, pqA, SK, G);
    maxpool_norms_kernel<64><<<NB * 64 * S / 256, 256, 0, stream>>>(bigA, psA, pqA,
                                                                    sa1_g[2], sa1_b[2], cf2, S);
  }

  // ---- propagate 512 -> 1024 ----
  fprop_kernel<64, true, N2><<<NB * (N1 / 256), 256, 0, stream>>>(pc1_l1, pc1_l2, cf2, cf1a, N1);

  // ---- SA2 (S=1024): 67->64->64->128 ----
  {
    const int S = N1, SK = S * KNN;
    const int G = NB * SK / 256;
    mm0p_kernel<64, 64><<<G, 256, 0, stream>>>(pc1_l1, cf1a, fps2, knn2, sa2_w[0],
                                               bigA, psA, pqA, S);
    mmnorms_kernel<64, 64, 64><<<G, 256, 0, stream>>>(bigA, sa2_w[1], psA, pqA,
                                                      sa2_g[0], sa2_b[0],
                                                      bigB, psB, pqB, SK, G);
    // D=128 as two halves in ONE launch (blocks [0,G) -> doff 0, [G,2G) -> doff 64)
    mmnorms_kernel<64, 64, 128><<<2 * G, 256, 0, stream>>>(bigB, sa2_w[2], psB, pqB,
                                                           sa2_g[1], sa2_b[1],
                                                           bigA, psA, pqA, SK, G);
    maxpool_norms_kernel<128><<<NB * 128 * S / 256, 256, 0, stream>>>(bigA, psA, pqA,
                                                                      sa2_g[2], sa2_b[2], cf1b, S);
  }

  // ---- final propagate 1024 -> 8192 into d_out ----
  fprop_kernel<128, false, N1><<<NB * (N0 / 256), 256, 0, stream>>>(pc1_l0, pc1_l1, cf1b,
                                                                    (float*)d_out, N0);
}